// Round 6
// baseline (247.516 us; speedup 1.0000x reference)
//
#include <hip/hip_runtime.h>
#include <math.h>

// ---------------- problem constants ----------------
#define MM 2048             // B*N keypoints
#define HOImg 512
#define GG 1024             // HG*WG
#define NCTRL 64
#define NPAR 132            // NPARAM*2

#define BN_S 0.9999950000374997f   // 1/sqrt(1+1e-5)

typedef __bf16 bf16x8 __attribute__((ext_vector_type(8)));
typedef float  f32x4  __attribute__((ext_vector_type(4)));

__device__ __forceinline__ unsigned short f2b(float v){
    unsigned u = __float_as_uint(v);
    unsigned r = (u + 0x7FFFu + ((u>>16)&1u)) >> 16;
    return (unsigned short)r;
}
__device__ __forceinline__ float b2f(unsigned short s){
    return __uint_as_float(((unsigned)s)<<16);
}

// async global->LDS, 16B per lane, LDS dest = uniform base + lane*16
__device__ __forceinline__ void gload_lds16(const void* g, void* l){
    __builtin_amdgcn_global_load_lds((const __attribute__((address_space(1))) void*)g,
                                     (__attribute__((address_space(3))) void*)l, 16, 0, 0);
}

// ===== prep_xb: x (4,64,128,128) f32 -> xp hi/lo bf16 [4][130][130][96] =====
__global__ __launch_bounds__(256) void prep_xb_k(const float* __restrict__ x,
    short* __restrict__ XH, short* __restrict__ XL)
{
    __shared__ float sT[64][65];
    const int xt = blockIdx.x, yo = blockIdx.y, b = blockIdx.z;
    const int tid = threadIdx.x;
    const int x0 = xt*64;

    if (yo == 0 || yo == 129){
        for (int e = tid; e < 6240; e += 256){      // half of 130*96
            int idx = xt*6240 + e;
            size_t o = (((size_t)b*130 + yo)*130 + idx/96)*96 + idx%96;
            XH[o] = 0; XL[o] = 0;
        }
        return;
    }
    const int ys = yo - 1;
    for (int e = tid; e < 64*64; e += 256) {
        int ci = e >> 6, xl = e & 63;
        sT[ci][xl] = x[(((size_t)b*64 + ci)*128 + ys)*128 + x0 + xl];
    }
    if (tid < 192){
        int ci = tid % 96; int pl = tid / 96;
        size_t o = (((size_t)b*130 + yo)*130 + (xt?129:0))*96 + ci;
        if (pl) XL[o] = 0; else XH[o] = 0;
    }
    __syncthreads();
    const float gy = -1.f + ys*(2.f/127.f);
    for (int e = tid; e < 64*96; e += 256) {
        int xl = e / 96, ci = e - xl*96;
        int xs = x0 + xl;
        float v;
        if (ci < 64) v = sT[ci][xl];
        else if (ci == 64) v = -1.f + xs*(2.f/127.f);
        else if (ci == 65) v = gy;
        else v = 0.f;
        unsigned short hi = f2b(v);
        unsigned short lo = f2b(v - b2f(hi));
        size_t o = (((size_t)b*130 + yo)*130 + (xs+1))*96 + ci;
        XH[o] = (short)hi; XL[o] = (short)lo;
    }
}

// ===== prep_misc: w1 prep (blocks 0..127), w2 prep (128..255), zero_h (256..767)
__global__ __launch_bounds__(256) void prep_misc_k(const float* __restrict__ w1,
    const float* __restrict__ w2, short* __restrict__ B1H, short* __restrict__ B1L,
    short* __restrict__ B2H, short* __restrict__ B2L,
    short* __restrict__ HH, short* __restrict__ HL)
{
    int bid = blockIdx.x;
    if (bid < 128){
        int co = bid;
        for (int e = threadIdx.x; e < 864; e += 256){
            int kp = e / 96, ci = e - kp*96;
            float v = 0.f;
            if (ci < 66){ int ky = kp/3, kx = kp - (kp/3)*3; v = w1[((co*66 + ci)*3 + ky)*3 + kx]; }
            unsigned short hi = f2b(v);
            B1H[co*864+e] = (short)hi; B1L[co*864+e] = (short)f2b(v - b2f(hi));
        }
    } else if (bid < 256){
        int co = bid - 128;
        for (int e = threadIdx.x; e < 1152; e += 256){
            int kp = e >> 7, ci = e & 127;
            int ky = kp/3, kx = kp - (kp/3)*3;
            float v = w2[((co*128 + ci)*3 + ky)*3 + kx];
            unsigned short hi = f2b(v);
            B2H[co*1152+e] = (short)hi; B2L[co*1152+e] = (short)f2b(v - b2f(hi));
        }
    } else {
        int t = (bid-256)*256 + threadIdx.x;
        if (t < 131072){
            int b = t >> 15; int r = t & 32767;
            int ci = r & 127; int col = (r>>7)&1; int y = r>>8;
            size_t o = (((size_t)b*128 + y)*130 + 128+col)*128 + ci;
            HH[o] = 0; HL[o] = 0;
        }
    }
}

// ===== MFMA implicit-GEMM 3x3 conv, split-bf16 3-pass =====
// __launch_bounds__(256,2): allow up to 256 VGPR (we're LDS/grid-capped at
// 2 waves/SIMD anyway) so the one-step-ahead A/B register prefetch survives
// regalloc instead of being folded into serial load->use.
template<int CCH, int HR, int HO_, int WO_, bool SPLIT>
__global__ __launch_bounds__(256, 2) void convm_k(
    const short* __restrict__ INh, const short* __restrict__ INl,
    const short* __restrict__ Bh, const short* __restrict__ Bl,
    short* __restrict__ Oh, short* __restrict__ Ol, float* __restrict__ Of)
{
    constexpr int WR = 130;
    constexpr int KTOT = 9*CCH;
    constexpr int NC = CCH/32;
    __shared__ __align__(16) short sA[2][16896];   // 2 bufs x (2 planes x 1056 int4)
    const int tid = threadIdx.x;
    const int x0 = blockIdx.x*64;
    const int y0 = blockIdx.y*2;
    const int b  = blockIdx.z;
    const int wv = tid>>6, lane = tid&63;
    const int wm = wv>>1, wn = wv&1;
    const int l15 = lane&15, lg = lane>>4;

    f32x4 acc[4][4];
    #pragma unroll
    for(int i=0;i<4;i++)
        #pragma unroll
        for(int j=0;j<4;j++) acc[i][j] = (f32x4)(0.0f);

    const int vofs = (wn*64 + l15)*KTOT + lg*8;

    auto stage = [&](int buf, int cc){
        const size_t inH = (((size_t)b*HR + y0)*WR + x0)*CCH + (size_t)cc*32;
        #pragma unroll
        for (int j=0;j<9;j++){
            int t = wv*528 + j*64 + lane;          // int4 slot 0..2111
            int pl = (t >= 1056) ? 1 : 0;
            int t2 = t - pl*1056;
            int q  = t2 >> 2;
            int r  = q/66, xx = q - r*66;
            int cb = (t2 & 3) ^ (xx & 3);          // inverse swizzle on source
            const short* src = (pl ? INl : INh) + inH + ((size_t)r*WR + xx)*CCH + cb*8;
            short* dst = &sA[buf][(wv*528 + j*64)*8];
            if (j < 8 || lane < 16) gload_lds16(src, dst);
        }
    };
    auto loadB = [&](bf16x8* dh, bf16x8* dl, int s){
        const int cc2 = s/9; const int kp2 = s - cc2*9;
        const int ko = kp2*CCH + cc2*32;
        #pragma unroll
        for (int nt=0;nt<4;nt++){
            dh[nt] = *(const bf16x8*)(Bh + vofs + nt*(16*KTOT) + ko);
            dl[nt] = *(const bf16x8*)(Bl + vofs + nt*(16*KTOT) + ko);
        }
    };
    auto loadA = [&](bf16x8* dAh, bf16x8* dAl, const short* sAc, int kp){
        const int ky = kp/3, kx = kp - (kp/3)*3;
        const int r = wm + ky;
        #pragma unroll
        for (int mt=0; mt<4; ++mt){
            int xx = mt*16 + l15 + kx;
            int slot = (r*66+xx)*4 + (lg ^ (xx&3));
            dAh[mt] = *(const bf16x8*)&sAc[slot*8];
            dAl[mt] = *(const bf16x8*)&sAc[8448 + slot*8];
        }
    };

    bf16x8 Bh2[2][4], Bl2[2][4];

    // prologue order matters for the counted vmcnt: stage0 (9), B (8), stage1 (9)
    stage(0, 0);
    loadB(Bh2[0], Bl2[0], 0);
    if (NC > 1) stage(1, 1);

    for (int cc = 0; cc < NC; ++cc){
        // drain everything except the most recent 9 DMA ops (= next chunk's stage)
        if (cc+1 < NC) { asm volatile("s_waitcnt vmcnt(9)" ::: "memory"); }
        else           { asm volatile("s_waitcnt vmcnt(0)" ::: "memory"); }
        __builtin_amdgcn_s_barrier();
        const short* sAc = &sA[cc&1][0];

        bf16x8 Ah2[2][4], Al2[2][4];
        loadA(Ah2[0], Al2[0], sAc, 0);
        #pragma unroll
        for (int kp=0;kp<9;kp++){
            const int cur = kp&1, nxt = cur^1;
            // prefetch next step (A from LDS; B from global — at kp==8 this is
            // the NEXT chunk's step-0 B, clamped on the last chunk)
            int s2 = cc*9 + kp + 1; if (s2 > NC*9-1) s2 = NC*9-1;
            if (kp < 8) loadA(Ah2[nxt], Al2[nxt], sAc, kp+1);
            loadB(Bh2[nxt], Bl2[nxt], s2);
            // pass 1: Ah*Bh — 16 independent MFMAs
            #pragma unroll
            for (int mt=0;mt<4;mt++)
                #pragma unroll
                for (int nt=0;nt<4;nt++)
                    acc[mt][nt] = __builtin_amdgcn_mfma_f32_16x16x32_bf16(Ah2[cur][mt], Bh2[cur][nt], acc[mt][nt],0,0,0);
            // pass 2: Ah*Bl
            #pragma unroll
            for (int mt=0;mt<4;mt++)
                #pragma unroll
                for (int nt=0;nt<4;nt++)
                    acc[mt][nt] = __builtin_amdgcn_mfma_f32_16x16x32_bf16(Ah2[cur][mt], Bl2[cur][nt], acc[mt][nt],0,0,0);
            // pass 3: Al*Bh
            #pragma unroll
            for (int mt=0;mt<4;mt++)
                #pragma unroll
                for (int nt=0;nt<4;nt++)
                    acc[mt][nt] = __builtin_amdgcn_mfma_f32_16x16x32_bf16(Al2[cur][mt], Bh2[cur][nt], acc[mt][nt],0,0,0);
        }
        // kp=8 left next-chunk B in slot 1 -> rotate to slot 0
        #pragma unroll
        for (int nt=0;nt<4;nt++){ Bh2[0][nt]=Bh2[1][nt]; Bl2[0][nt]=Bl2[1][nt]; }
        asm volatile("s_waitcnt lgkmcnt(0)" ::: "memory");   // own ds_reads done
        __builtin_amdgcn_s_barrier();                        // all waves done with buf
        if (cc+2 < NC) stage(cc&1, cc+2);                    // restage this buf async
    }

    const int y = y0 + wm;
    #pragma unroll
    for (int mt=0;mt<4;mt++){
        #pragma unroll
        for (int reg=0;reg<4;reg++){
            const int rx = mt*16 + lg*4 + reg;
            const int xo = x0 + rx;
            if (WO_ == 128 || xo < WO_){
                #pragma unroll
                for (int nt=0;nt<4;nt++){
                    const int co = wn*64 + nt*16 + l15;
                    float v = fmaxf(acc[mt][nt][reg]*BN_S, 0.f);
                    if (SPLIT){
                        size_t o = (((size_t)b*HO_ + y)*WR + xo)*128 + co;
                        unsigned short hi = f2b(v);
                        Oh[o] = (short)hi; Ol[o] = (short)f2b(v - b2f(hi));
                    } else {
                        size_t o = (((size_t)b*HO_ + y)*(size_t)WO_ + xo)*128 + co;
                        Of[o] = v;
                    }
                }
            }
        }
    }
}

// ===== interp: bilinear sample Theta (channels-last) at keypoints -> th0 (2048,128)
__global__ __launch_bounds__(128) void interp_k(const float* __restrict__ Theta,
    const int* __restrict__ kp, float* __restrict__ out)
{
    int m = blockIdx.x;
    int c = threadIdx.x;
    int b = m >> 9;
    float ix = (float)kp[m*2+0]/511.f*125.f;
    float iy = (float)kp[m*2+1]/511.f*125.f;
    float x0 = floorf(ix), y0 = floorf(iy);
    float wx = ix-x0, wy = iy-y0;
    const float* f = Theta + (size_t)b*126*126*128 + c;
    float r = 0.f;
    #pragma unroll
    for (int t=0;t<4;t++){
        float xi = x0 + (t&1), yi = y0 + (t>>1);
        float wt = ((t&1)?wx:(1.f-wx)) * ((t>>1)?wy:(1.f-wy));
        bool v = (xi>=0.f)&&(xi<=125.f)&&(yi>=0.f)&&(yi<=125.f);
        int xc=(int)fminf(fmaxf(xi,0.f),125.f), yc=(int)fminf(fmaxf(yi,0.f),125.f);
        r += f[((size_t)yc*126 + xc)*128]*(v?wt:0.f);
    }
    out[m*128+c] = r;
}

// ===== linear layers =====
__global__ __launch_bounds__(256) void lin1_k(const float* __restrict__ xin,
    const float* __restrict__ w, const float* __restrict__ bias, float* __restrict__ out)
{
    __shared__ float sx[8][128];
    int tid = threadIdx.x;
    int m0 = blockIdx.x*8;
    for (int e = tid; e < 8*128; e += 256) sx[e>>7][e&127] = xin[(m0 + (e>>7))*128 + (e&127)];
    __syncthreads();
    int o = tid;
    float acc[8] = {0,0,0,0,0,0,0,0};
    const float* wr = w + o*128;
    for (int i=0;i<128;i++){
        float wv = wr[i];
        #pragma unroll
        for (int j=0;j<8;j++) acc[j] += sx[j][i]*wv;
    }
    float bv = bias[o];
    #pragma unroll
    for (int j=0;j<8;j++) out[(m0+j)*256 + o] = fmaxf((acc[j]+bv)*BN_S, 0.f);
}

__global__ __launch_bounds__(256) void lin2_k(const float* __restrict__ xin,
    const float* __restrict__ w, const float* __restrict__ bias, float* __restrict__ out)
{
    __shared__ float sx[8][256];
    int tid = threadIdx.x;
    int m0 = blockIdx.x*8;
    for (int e = tid; e < 8*256; e += 256) sx[e>>8][e&255] = xin[(m0 + (e>>8))*256 + (e&255)];
    __syncthreads();
    int o = tid;
    float acc[8] = {0,0,0,0,0,0,0,0};
    const float* wr = w + o*256;
    for (int i=0;i<256;i++){
        float wv = wr[i];
        #pragma unroll
        for (int j=0;j<8;j++) acc[j] += sx[j][i]*wv;
    }
    float bv = bias[o];
    #pragma unroll
    for (int j=0;j<8;j++) out[(m0+j)*256 + o] = fmaxf(acc[j]+bv, 0.f);
}

__global__ __launch_bounds__(256) void lin3_k(const float* __restrict__ xin,
    const float* __restrict__ w, const float* __restrict__ bias, float* __restrict__ out)
{
    __shared__ float sx[8][256];
    int tid = threadIdx.x;
    int m0 = blockIdx.x*8;
    for (int e = tid; e < 8*256; e += 256) sx[e>>8][e&255] = xin[(m0 + (e>>8))*256 + (e&255)];
    __syncthreads();
    int o = tid;
    if (o < NPAR){
        float acc[8] = {0,0,0,0,0,0,0,0};
        const float* wr = w + o*256;
        for (int i=0;i<256;i++){
            float wv = wr[i];
            #pragma unroll
            for (int j=0;j<8;j++) acc[j] += sx[j][i]*wv;
        }
        float bv = bias[o];
        #pragma unroll
        for (int j=0;j<8;j++) out[(m0+j)*NPAR + o] = tanhf(acc[j]+bv);
    }
}

// ===== constants: reduce (1 block) + Ut fill (64 blocks) =====
__global__ __launch_bounds__(1024) void consts_red_k(float* __restrict__ cbuf,
    float* __restrict__ pgn, float* __restrict__ ctrl)
{
    __shared__ float sm[1024];
    int g = threadIdx.x;
    int i = g >> 5, j = g & 31;
    float xs = (j + 0.5f)*(2.0f/32.0f) - 1.0f;
    float ys = (i + 0.5f)*(2.0f/32.0f) - 1.0f;
    float norm = (xs + 1.0f)*0.5f;
    float r_ = 1.0f + norm*31.0f;
    float r_s = (r_ - 1.0f)/31.0f*2.0f*32.0f/512.0f;
    float t_s = (ys + 1.0f)*3.14159265358979323846f;
    float bx = r_s*cosf(t_s);
    float by = r_s*sinf(t_s);

    float red[4];
    for (int pass=0; pass<4; ++pass){
        float v = (pass<2) ? bx : by;
        bool isMax = (pass&1);
        sm[g] = v; __syncthreads();
        for (int s=512; s>0; s>>=1){
            if (g < s){ float a=sm[g], b2=sm[g+s]; sm[g] = isMax ? fmaxf(a,b2) : fminf(a,b2); }
            __syncthreads();
        }
        red[pass] = sm[0]; __syncthreads();
    }
    float minx=red[0], maxx=red[1], miny=red[2], maxy=red[3];
    float ptpx = maxx-minx, ptpy = maxy-miny;
    if (g == 0){ cbuf[0]=minx; cbuf[1]=miny; cbuf[2]=ptpx; cbuf[3]=ptpy; }

    float pgx = (bx - minx)/(ptpx + 1e-8f)*0.3f + 0.35f;
    float pgy = (by - miny)/(ptpy + 1e-8f)*0.3f + 0.35f;
    pgn[2*g]   = pgx;
    pgn[2*g+1] = pgy;
    if ((i&3)==0 && (j&3)==0){ int t = (i>>2)*8 + (j>>2); ctrl[t*2]=pgx; ctrl[t*2+1]=pgy; }
}

__global__ __launch_bounds__(256) void ut_fill_k(const float* __restrict__ pgn,
    const float* __restrict__ ctrl, float* __restrict__ Ut)
{
    int t = blockIdx.x;
    int g = threadIdx.x;
    float cx = ctrl[t*2], cy = ctrl[t*2+1];
    float c2 = cx*cx + cy*cy;
    #pragma unroll
    for (int k=0;k<4;k++){
        int gg = g + k*256;
        float px = pgn[2*gg], py = pgn[2*gg+1];
        float r2 = fmaxf((px*px+py*py) + c2 - 2.0f*(px*cx+py*cy), 0.0f);
        float D = sqrtf(r2 + 1e-12f);
        Ut[t*GG+gg] = r2*logf(D + 1e-6f);
    }
}

// ===== warp + final image sampling, 4 keypoints per block =====
__global__ __launch_bounds__(256) void warp_sample4_k(const float* __restrict__ theta,
    const int* __restrict__ kp, const float* __restrict__ Ut,
    const float* __restrict__ pgn, const float* __restrict__ cbuf,
    const float* __restrict__ imgs, float* __restrict__ out)
{
    __shared__ float sth[4][132];
    __shared__ float sw0[4][64], sw1[4][64];
    __shared__ float sa[4][8];
    __shared__ float sv[4][2];
    const int m0 = blockIdx.x*4, tid = threadIdx.x;
    const int b = m0 >> 9;
    for (int e=tid; e<4*132; e+=256) sth[e/132][e%132] = theta[(size_t)(m0 + e/132)*NPAR + (e%132)];
    __syncthreads();
    {   // e = tid covers exactly 4*64 = 256
        int kpi = tid>>6, t = tid&63;
        if (t > 0){ sw0[kpi][t] = sth[kpi][2*t-2]; sw1[kpi][t] = sth[kpi][2*t-1]; }
        else {
            float s0=0.f, s1=0.f;
            for (int p=0;p<63;p++){ s0 += sth[kpi][2*p]; s1 += sth[kpi][2*p+1]; }
            sw0[kpi][0] = -s0; sw1[kpi][0] = -s1;
        }
    }
    if (tid < 24){ int kpi = tid/6, j = tid%6; sa[kpi][j] = sth[kpi][126+j]; }
    if (tid < 8){
        int kpi = tid>>1, c = tid&1;
        sv[kpi][c] = cbuf[c] + ((float)kp[(m0+kpi)*2+c]/512.f*2.f - 1.f);
    }
    __syncthreads();

    const float ptpx = cbuf[2], ptpy = cbuf[3];
    const int g0 = tid*4;
    float bx[4][4] = {}, by[4][4] = {};
    const f32x4* Ut4 = (const f32x4*)Ut;
    #pragma unroll 8
    for (int t=0;t<NCTRL;t++){
        f32x4 u = Ut4[t*256 + tid];
        #pragma unroll
        for (int kpi=0;kpi<4;kpi++){
            float s0 = sw0[kpi][t], s1 = sw1[kpi][t];
            #pragma unroll
            for (int i=0;i<4;i++){ bx[kpi][i] += u[i]*s0; by[kpi][i] += u[i]*s1; }
        }
    }

    f32x4 pga = *(const f32x4*)&pgn[2*g0];
    f32x4 pgb = *(const f32x4*)&pgn[2*g0+4];
    float px[4] = {pga[0], pga[2], pgb[0], pgb[2]};
    float py[4] = {pga[1], pga[3], pgb[1], pgb[3]};
    const float* ic0 = imgs + (size_t)b*3*HOImg*HOImg;
    const float* ic1 = ic0 + (size_t)HOImg*HOImg;
    const float* ic2 = ic1 + (size_t)HOImg*HOImg;

    #pragma unroll
    for (int kpi=0;kpi<4;kpi++){
        float a00=sa[kpi][0], a01=sa[kpi][1], a10=sa[kpi][2];
        float a11=sa[kpi][3], a20=sa[kpi][4], a21=sa[kpi][5];
        float vminx = sv[kpi][0], vminy = sv[kpi][1];
        f32x4 o0, o1, o2;
        #pragma unroll
        for (int i=0;i<4;i++){
            float zx = a00 + a10*px[i] + a20*py[i];
            float zy = a01 + a11*px[i] + a21*py[i];
            float wnx = px[i] + (zx + bx[kpi][i]);
            float wny = py[i] + (zy + by[kpi][i]);
            float wxr = (wnx - 0.35f)/0.3f*ptpx + vminx;
            float wyr = (wny - 0.35f)/0.3f*ptpy + vminy;
            float ix = ((wxr + 1.f)*512.f - 1.f)*0.5f;
            float iy = ((wyr + 1.f)*512.f - 1.f)*0.5f;
            float x0f = floorf(ix), y0f = floorf(iy);
            float fx = ix-x0f, fy = iy-y0f;
            float w00=(1.f-fx)*(1.f-fy), w10=fx*(1.f-fy), w01=(1.f-fx)*fy, w11=fx*fy;
            bool vx0 = (x0f>=0.f)&&(x0f<=511.f), vx1 = (x0f+1.f>=0.f)&&(x0f+1.f<=511.f);
            bool vy0 = (y0f>=0.f)&&(y0f<=511.f), vy1 = (y0f+1.f>=0.f)&&(y0f+1.f<=511.f);
            float m00 = (vx0&&vy0)?w00:0.f;
            float m10 = (vx1&&vy0)?w10:0.f;
            float m01 = (vx0&&vy1)?w01:0.f;
            float m11 = (vx1&&vy1)?w11:0.f;
            int X0 = (int)fminf(fmaxf(x0f,0.f),511.f);
            int X1 = (int)fminf(fmaxf(x0f+1.f,0.f),511.f);
            int Y0 = (int)fminf(fmaxf(y0f,0.f),511.f);
            int Y1 = (int)fminf(fmaxf(y0f+1.f,0.f),511.f);
            int i00 = Y0*HOImg+X0, i10 = Y0*HOImg+X1, i01 = Y1*HOImg+X0, i11 = Y1*HOImg+X1;
            o0[i] = ic0[i00]*m00 + ic0[i10]*m10 + ic0[i01]*m01 + ic0[i11]*m11;
            o1[i] = ic1[i00]*m00 + ic1[i10]*m10 + ic1[i01]*m01 + ic1[i11]*m11;
            o2[i] = ic2[i00]*m00 + ic2[i10]*m10 + ic2[i01]*m01 + ic2[i11]*m11;
        }
        const int m = m0 + kpi;
        *(f32x4*)&out[((size_t)(m*3+0))*GG + g0] = o0;
        *(f32x4*)&out[((size_t)(m*3+1))*GG + g0] = o1;
        *(f32x4*)&out[((size_t)(m*3+2))*GG + g0] = o2;
    }
}

// ============================ launcher =======================================
extern "C" void kernel_launch(void* const* d_in, const int* in_sizes, int n_in,
                              void* d_out, int out_size, void* d_ws, size_t ws_size,
                              hipStream_t stream)
{
    const float* x    = (const float*)d_in[0];
    const float* imgs = (const float*)d_in[1];
    const int*   kp   = (const int*)d_in[2];
    const float* c1w  = (const float*)d_in[3];
    const float* c2w  = (const float*)d_in[4];
    const float* l1w  = (const float*)d_in[5];
    const float* l1b  = (const float*)d_in[6];
    const float* l2w  = (const float*)d_in[7];
    const float* l2b  = (const float*)d_in[8];
    const float* l3w  = (const float*)d_in[9];
    const float* l3b  = (const float*)d_in[10];
    float* out = (float*)d_out;

    char* W = (char*)d_ws;
    short* xph   = (short*)(W + 0);                    // 12,979,200 B
    short* xpl   = (short*)(W + 12979200);             // 12,979,200 B
    float* Theta = (float*)(W + 0);                    // 32,514,048 B (aliases xp)
    constexpr size_t OFF_HH = 32514048;
    constexpr size_t OFF_HL = OFF_HH + 17039360;
    short* hh = (short*)(W + OFF_HH);
    short* hl = (short*)(W + OFF_HL);
    float* th0   = (float*)(W + OFF_HH);               // aliases h after conv2
    float* th1   = (float*)(W + OFF_HH + 1048576);
    float* th2   = (float*)(W + OFF_HH + 3145728);
    float* theta = (float*)(W + OFF_HH + 5242880);
    float* Ut    = (float*)(W + OFF_HH + 6324224);
    float* pgn   = (float*)(W + OFF_HH + 6586368);
    float* cbuf  = (float*)(W + OFF_HH + 6594560);
    float* ctrl  = (float*)(W + OFF_HH + 6594816);     // 512 B
    constexpr size_t OFF_B = OFF_HL + 17039360;
    short* B1h = (short*)(W + OFF_B);
    short* B1l = (short*)(W + OFF_B + 221184);
    short* B2h = (short*)(W + OFF_B + 442368);
    short* B2l = (short*)(W + OFF_B + 737280);

    hipLaunchKernelGGL(prep_xb_k, dim3(2,130,4), dim3(256), 0, stream, x, xph, xpl);
    hipLaunchKernelGGL(prep_misc_k, dim3(768), dim3(256), 0, stream,
                       c1w, c2w, B1h, B1l, B2h, B2l, hh, hl);

    hipLaunchKernelGGL((convm_k<96,130,128,128,true>), dim3(2,64,4), dim3(256), 0, stream,
                       xph, xpl, B1h, B1l, hh, hl, (float*)nullptr);
    hipLaunchKernelGGL((convm_k<128,128,126,126,false>), dim3(2,63,4), dim3(256), 0, stream,
                       hh, hl, B2h, B2l, (short*)nullptr, (short*)nullptr, Theta);

    hipLaunchKernelGGL(interp_k, dim3(MM), dim3(128), 0, stream, Theta, kp, th0);
    hipLaunchKernelGGL(lin1_k, dim3(MM/8), dim3(256), 0, stream, th0, l1w, l1b, th1);
    hipLaunchKernelGGL(lin2_k, dim3(MM/8), dim3(256), 0, stream, th1, l2w, l2b, th2);
    hipLaunchKernelGGL(lin3_k, dim3(MM/8), dim3(256), 0, stream, th2, l3w, l3b, theta);
    hipLaunchKernelGGL(consts_red_k, dim3(1), dim3(1024), 0, stream, cbuf, pgn, ctrl);
    hipLaunchKernelGGL(ut_fill_k, dim3(64), dim3(256), 0, stream, pgn, ctrl, Ut);
    hipLaunchKernelGGL(warp_sample4_k, dim3(MM/4), dim3(256), 0, stream,
                       theta, kp, Ut, pgn, cbuf, imgs, out);
}

// Round 7
// 184.527 us; speedup vs baseline: 1.3414x; 1.3414x over previous
//
#include <hip/hip_runtime.h>
#include <math.h>

// ---------------- problem constants ----------------
#define MM 2048             // B*N keypoints
#define HOImg 512
#define GG 1024             // HG*WG
#define NCTRL 64
#define NPAR 132            // NPARAM*2

#define BN_S 0.9999950000374997f   // 1/sqrt(1+1e-5)

typedef __bf16 bf16x8 __attribute__((ext_vector_type(8)));
typedef float  f32x4  __attribute__((ext_vector_type(4)));

__device__ __forceinline__ unsigned short f2b(float v){
    unsigned u = __float_as_uint(v);
    unsigned r = (u + 0x7FFFu + ((u>>16)&1u)) >> 16;
    return (unsigned short)r;
}
__device__ __forceinline__ float b2f(unsigned short s){
    return __uint_as_float(((unsigned)s)<<16);
}

// async global->LDS, 16B per lane, LDS dest = uniform base + lane*16
__device__ __forceinline__ void gload_lds16(const void* g, void* l){
    __builtin_amdgcn_global_load_lds((const __attribute__((address_space(1))) void*)g,
                                     (__attribute__((address_space(3))) void*)l, 16, 0, 0);
}

// ===== prep_xb: x (4,64,128,128) f32 -> xp bf16 [4][130][130][96] =====
// channels-last, 1-px zero border, ci64=gx, ci65=gy, 66..95 = 0
__global__ __launch_bounds__(256) void prep_xb_k(const float* __restrict__ x,
    short* __restrict__ XH)
{
    __shared__ float sT[64][65];
    const int xt = blockIdx.x, yo = blockIdx.y, b = blockIdx.z;
    const int tid = threadIdx.x;
    const int x0 = xt*64;

    if (yo == 0 || yo == 129){
        for (int e = tid; e < 6240; e += 256){      // half of 130*96
            int idx = xt*6240 + e;
            size_t o = (((size_t)b*130 + yo)*130 + idx/96)*96 + idx%96;
            XH[o] = 0;
        }
        return;
    }
    const int ys = yo - 1;
    for (int e = tid; e < 64*64; e += 256) {
        int ci = e >> 6, xl = e & 63;
        sT[ci][xl] = x[(((size_t)b*64 + ci)*128 + ys)*128 + x0 + xl];
    }
    if (tid < 96){
        size_t o = (((size_t)b*130 + yo)*130 + (xt?129:0))*96 + tid;
        XH[o] = 0;
    }
    __syncthreads();
    const float gy = -1.f + ys*(2.f/127.f);
    for (int e = tid; e < 64*96; e += 256) {
        int xl = e / 96, ci = e - xl*96;
        int xs = x0 + xl;
        float v;
        if (ci < 64) v = sT[ci][xl];
        else if (ci == 64) v = -1.f + xs*(2.f/127.f);
        else if (ci == 65) v = gy;
        else v = 0.f;
        size_t o = (((size_t)b*130 + yo)*130 + (xs+1))*96 + ci;
        XH[o] = (short)f2b(v);
    }
}

// ===== prep_misc: w1 prep (blocks 0..127), w2 prep (128..255), zero_h (256..767)
__global__ __launch_bounds__(256) void prep_misc_k(const float* __restrict__ w1,
    const float* __restrict__ w2, short* __restrict__ B1H,
    short* __restrict__ B2H, short* __restrict__ HH)
{
    int bid = blockIdx.x;
    if (bid < 128){
        int co = bid;
        for (int e = threadIdx.x; e < 864; e += 256){
            int kp = e / 96, ci = e - kp*96;
            float v = 0.f;
            if (ci < 66){ int ky = kp/3, kx = kp - (kp/3)*3; v = w1[((co*66 + ci)*3 + ky)*3 + kx]; }
            B1H[co*864+e] = (short)f2b(v);
        }
    } else if (bid < 256){
        int co = bid - 128;
        for (int e = threadIdx.x; e < 1152; e += 256){
            int kp = e >> 7, ci = e & 127;
            int ky = kp/3, kx = kp - (kp/3)*3;
            float v = w2[((co*128 + ci)*3 + ky)*3 + kx];
            B2H[co*1152+e] = (short)f2b(v);
        }
    } else {
        int t = (bid-256)*256 + threadIdx.x;
        if (t < 131072){
            int b = t >> 15; int r = t & 32767;
            int ci = r & 127; int col = (r>>7)&1; int y = r>>8;
            size_t o = (((size_t)b*128 + y)*130 + 128+col)*128 + ci;
            HH[o] = 0;
        }
    }
}

// ===== MFMA implicit-GEMM 3x3 conv, PLAIN bf16 single pass =====
// Block: 2 out rows x 32 cols x ALL 128 co; 4 waves, each wave owns 32 co
// (co = wv*32 + nt*16 + l15) and the full 2x32 spatial patch (4 mt-frags).
// A tile per chunk: 4 rows x 34 x 32ci bf16 = 8704 B, double-buffered (17.4 KB).
// Bank swizzle: slot = (r*34+xx)*4 + (lg ^ ((xx>>1)&3)) -> 64 lanes spread over
// all 8 bank-groups (2-way = free). Staged via global_load_lds with
// inverse-swizzled global source (linear LDS dest), 3 DMA ops per wave.
template<int CCH, int HR, int HO_, int WO_, bool SPLIT>
__global__ __launch_bounds__(256, 4) void convm_k(
    const short* __restrict__ IN, const short* __restrict__ Bm,
    short* __restrict__ Oh, float* __restrict__ Of)
{
    constexpr int WR = 130;
    constexpr int KTOT = 9*CCH;
    constexpr int NC = CCH/32;
    __shared__ __align__(16) short sA[2][4352];    // 2 bufs x 544 int4
    const int tid = threadIdx.x;
    const int x0 = blockIdx.x*32;
    const int y0 = blockIdx.y*2;
    const int b  = blockIdx.z;
    const int wv = tid>>6, lane = tid&63;
    const int l15 = lane&15, lg = lane>>4;

    f32x4 acc[4][2];
    #pragma unroll
    for(int i=0;i<4;i++){ acc[i][0] = (f32x4)(0.0f); acc[i][1] = (f32x4)(0.0f); }

    const int vofs = (wv*32 + l15)*KTOT + lg*8;

    auto stage = [&](int buf, int cc){
        const size_t inH = (((size_t)b*HR + y0)*WR + x0)*CCH + (size_t)cc*32;
        #pragma unroll
        for (int j=0;j<3;j++){
            int s = wv*136 + j*64 + lane;          // int4 slot 0..543
            int q = s >> 2;
            int r = q/34, xx = q - r*34;
            int cb = (s & 3) ^ ((xx>>1) & 3);      // inverse swizzle on source
            const short* src = IN + inH + ((size_t)r*WR + xx)*CCH + cb*8;
            short* dst = &sA[buf][(wv*136 + j*64)*8];
            if (j < 2 || lane < 8) gload_lds16(src, dst);
        }
    };
    auto loadA = [&](bf16x8* dA, const short* sAc, int kp){
        const int ky = kp/3, kx = kp - (kp/3)*3;
        #pragma unroll
        for (int mt=0; mt<4; ++mt){
            int r = (mt>>1) + ky;
            int xx = (mt&1)*16 + l15 + kx;
            int slot = (r*34+xx)*4 + (lg ^ ((xx>>1)&3));
            dA[mt] = *(const bf16x8*)&sAc[slot*8];
        }
    };

    // prologue: stage chunk 0 (3 ops/wave), then chunk 1 (3 ops/wave)
    stage(0, 0);
    if (NC > 1) stage(1, 1);

    for (int cc = 0; cc < NC; ++cc){
        // drain all but the newest 3 DMA ops (= next chunk's stage, still in flight)
        if (cc+1 < NC) { asm volatile("s_waitcnt vmcnt(3)" ::: "memory"); }
        else           { asm volatile("s_waitcnt vmcnt(0)" ::: "memory"); }
        __builtin_amdgcn_s_barrier();
        const short* sAc = &sA[cc&1][0];
        #pragma unroll
        for (int kp=0;kp<9;kp++){
            bf16x8 A[4], Bv[2];
            loadA(A, sAc, kp);
            const int ko = kp*CCH + cc*32;
            Bv[0] = *(const bf16x8*)(Bm + vofs + ko);
            Bv[1] = *(const bf16x8*)(Bm + vofs + 16*KTOT + ko);
            #pragma unroll
            for (int mt=0;mt<4;mt++){
                acc[mt][0] = __builtin_amdgcn_mfma_f32_16x16x32_bf16(A[mt], Bv[0], acc[mt][0],0,0,0);
                acc[mt][1] = __builtin_amdgcn_mfma_f32_16x16x32_bf16(A[mt], Bv[1], acc[mt][1],0,0,0);
            }
        }
        asm volatile("s_waitcnt lgkmcnt(0)" ::: "memory");   // own ds_reads done
        __builtin_amdgcn_s_barrier();                        // all waves done with buf
        if (cc+2 < NC) stage(cc&1, cc+2);                    // restage this buf async
    }

    #pragma unroll
    for (int mt=0;mt<4;mt++){
        const int y = y0 + (mt>>1);
        #pragma unroll
        for (int reg=0;reg<4;reg++){
            const int xo = x0 + (mt&1)*16 + lg*4 + reg;
            if (WO_ == 128 || xo < WO_){
                #pragma unroll
                for (int nt=0;nt<2;nt++){
                    const int co = wv*32 + nt*16 + l15;
                    float v = fmaxf(acc[mt][nt][reg]*BN_S, 0.f);
                    if (SPLIT){
                        size_t o = (((size_t)b*HO_ + y)*WR + xo)*128 + co;
                        Oh[o] = (short)f2b(v);
                    } else {
                        size_t o = (((size_t)b*HO_ + y)*(size_t)WO_ + xo)*128 + co;
                        Of[o] = v;
                    }
                }
            }
        }
    }
}

// ===== interp: bilinear sample Theta (channels-last) at keypoints -> th0 (2048,128)
__global__ __launch_bounds__(128) void interp_k(const float* __restrict__ Theta,
    const int* __restrict__ kp, float* __restrict__ out)
{
    int m = blockIdx.x;
    int c = threadIdx.x;
    int b = m >> 9;
    float ix = (float)kp[m*2+0]/511.f*125.f;
    float iy = (float)kp[m*2+1]/511.f*125.f;
    float x0 = floorf(ix), y0 = floorf(iy);
    float wx = ix-x0, wy = iy-y0;
    const float* f = Theta + (size_t)b*126*126*128 + c;
    float r = 0.f;
    #pragma unroll
    for (int t=0;t<4;t++){
        float xi = x0 + (t&1), yi = y0 + (t>>1);
        float wt = ((t&1)?wx:(1.f-wx)) * ((t>>1)?wy:(1.f-wy));
        bool v = (xi>=0.f)&&(xi<=125.f)&&(yi>=0.f)&&(yi<=125.f);
        int xc=(int)fminf(fmaxf(xi,0.f),125.f), yc=(int)fminf(fmaxf(yi,0.f),125.f);
        r += f[((size_t)yc*126 + xc)*128]*(v?wt:0.f);
    }
    out[m*128+c] = r;
}

// ===== linear layers =====
__global__ __launch_bounds__(256) void lin1_k(const float* __restrict__ xin,
    const float* __restrict__ w, const float* __restrict__ bias, float* __restrict__ out)
{
    __shared__ float sx[8][128];
    int tid = threadIdx.x;
    int m0 = blockIdx.x*8;
    for (int e = tid; e < 8*128; e += 256) sx[e>>7][e&127] = xin[(m0 + (e>>7))*128 + (e&127)];
    __syncthreads();
    int o = tid;
    float acc[8] = {0,0,0,0,0,0,0,0};
    const float* wr = w + o*128;
    for (int i=0;i<128;i++){
        float wv = wr[i];
        #pragma unroll
        for (int j=0;j<8;j++) acc[j] += sx[j][i]*wv;
    }
    float bv = bias[o];
    #pragma unroll
    for (int j=0;j<8;j++) out[(m0+j)*256 + o] = fmaxf((acc[j]+bv)*BN_S, 0.f);
}

__global__ __launch_bounds__(256) void lin2_k(const float* __restrict__ xin,
    const float* __restrict__ w, const float* __restrict__ bias, float* __restrict__ out)
{
    __shared__ float sx[8][256];
    int tid = threadIdx.x;
    int m0 = blockIdx.x*8;
    for (int e = tid; e < 8*256; e += 256) sx[e>>8][e&255] = xin[(m0 + (e>>8))*256 + (e&255)];
    __syncthreads();
    int o = tid;
    float acc[8] = {0,0,0,0,0,0,0,0};
    const float* wr = w + o*256;
    for (int i=0;i<256;i++){
        float wv = wr[i];
        #pragma unroll
        for (int j=0;j<8;j++) acc[j] += sx[j][i]*wv;
    }
    float bv = bias[o];
    #pragma unroll
    for (int j=0;j<8;j++) out[(m0+j)*256 + o] = fmaxf(acc[j]+bv, 0.f);
}

__global__ __launch_bounds__(256) void lin3_k(const float* __restrict__ xin,
    const float* __restrict__ w, const float* __restrict__ bias, float* __restrict__ out)
{
    __shared__ float sx[8][256];
    int tid = threadIdx.x;
    int m0 = blockIdx.x*8;
    for (int e = tid; e < 8*256; e += 256) sx[e>>8][e&255] = xin[(m0 + (e>>8))*256 + (e&255)];
    __syncthreads();
    int o = tid;
    if (o < NPAR){
        float acc[8] = {0,0,0,0,0,0,0,0};
        const float* wr = w + o*256;
        for (int i=0;i<256;i++){
            float wv = wr[i];
            #pragma unroll
            for (int j=0;j<8;j++) acc[j] += sx[j][i]*wv;
        }
        float bv = bias[o];
        #pragma unroll
        for (int j=0;j<8;j++) out[(m0+j)*NPAR + o] = tanhf(acc[j]+bv);
    }
}

// ===== constants: reduce (1 block) + Ut fill (64 blocks) =====
__global__ __launch_bounds__(1024) void consts_red_k(float* __restrict__ cbuf,
    float* __restrict__ pgn, float* __restrict__ ctrl)
{
    __shared__ float sm[1024];
    int g = threadIdx.x;
    int i = g >> 5, j = g & 31;
    float xs = (j + 0.5f)*(2.0f/32.0f) - 1.0f;
    float ys = (i + 0.5f)*(2.0f/32.0f) - 1.0f;
    float norm = (xs + 1.0f)*0.5f;
    float r_ = 1.0f + norm*31.0f;
    float r_s = (r_ - 1.0f)/31.0f*2.0f*32.0f/512.0f;
    float t_s = (ys + 1.0f)*3.14159265358979323846f;
    float bx = r_s*cosf(t_s);
    float by = r_s*sinf(t_s);

    float red[4];
    for (int pass=0; pass<4; ++pass){
        float v = (pass<2) ? bx : by;
        bool isMax = (pass&1);
        sm[g] = v; __syncthreads();
        for (int s=512; s>0; s>>=1){
            if (g < s){ float a=sm[g], b2=sm[g+s]; sm[g] = isMax ? fmaxf(a,b2) : fminf(a,b2); }
            __syncthreads();
        }
        red[pass] = sm[0]; __syncthreads();
    }
    float minx=red[0], maxx=red[1], miny=red[2], maxy=red[3];
    float ptpx = maxx-minx, ptpy = maxy-miny;
    if (g == 0){ cbuf[0]=minx; cbuf[1]=miny; cbuf[2]=ptpx; cbuf[3]=ptpy; }

    float pgx = (bx - minx)/(ptpx + 1e-8f)*0.3f + 0.35f;
    float pgy = (by - miny)/(ptpy + 1e-8f)*0.3f + 0.35f;
    pgn[2*g]   = pgx;
    pgn[2*g+1] = pgy;
    if ((i&3)==0 && (j&3)==0){ int t = (i>>2)*8 + (j>>2); ctrl[t*2]=pgx; ctrl[t*2+1]=pgy; }
}

__global__ __launch_bounds__(256) void ut_fill_k(const float* __restrict__ pgn,
    const float* __restrict__ ctrl, float* __restrict__ Ut)
{
    int t = blockIdx.x;
    int g = threadIdx.x;
    float cx = ctrl[t*2], cy = ctrl[t*2+1];
    float c2 = cx*cx + cy*cy;
    #pragma unroll
    for (int k=0;k<4;k++){
        int gg = g + k*256;
        float px = pgn[2*gg], py = pgn[2*gg+1];
        float r2 = fmaxf((px*px+py*py) + c2 - 2.0f*(px*cx+py*cy), 0.0f);
        float D = sqrtf(r2 + 1e-12f);
        Ut[t*GG+gg] = r2*logf(D + 1e-6f);
    }
}

// ===== warp + final image sampling, 4 keypoints per block =====
__global__ __launch_bounds__(256) void warp_sample4_k(const float* __restrict__ theta,
    const int* __restrict__ kp, const float* __restrict__ Ut,
    const float* __restrict__ pgn, const float* __restrict__ cbuf,
    const float* __restrict__ imgs, float* __restrict__ out)
{
    __shared__ float sth[4][132];
    __shared__ float sw0[4][64], sw1[4][64];
    __shared__ float sa[4][8];
    __shared__ float sv[4][2];
    const int m0 = blockIdx.x*4, tid = threadIdx.x;
    const int b = m0 >> 9;
    for (int e=tid; e<4*132; e+=256) sth[e/132][e%132] = theta[(size_t)(m0 + e/132)*NPAR + (e%132)];
    __syncthreads();
    {   // e = tid covers exactly 4*64 = 256
        int kpi = tid>>6, t = tid&63;
        if (t > 0){ sw0[kpi][t] = sth[kpi][2*t-2]; sw1[kpi][t] = sth[kpi][2*t-1]; }
        else {
            float s0=0.f, s1=0.f;
            for (int p=0;p<63;p++){ s0 += sth[kpi][2*p]; s1 += sth[kpi][2*p+1]; }
            sw0[kpi][0] = -s0; sw1[kpi][0] = -s1;
        }
    }
    if (tid < 24){ int kpi = tid/6, j = tid%6; sa[kpi][j] = sth[kpi][126+j]; }
    if (tid < 8){
        int kpi = tid>>1, c = tid&1;
        sv[kpi][c] = cbuf[c] + ((float)kp[(m0+kpi)*2+c]/512.f*2.f - 1.f);
    }
    __syncthreads();

    const float ptpx = cbuf[2], ptpy = cbuf[3];
    const int g0 = tid*4;
    float bx[4][4] = {}, by[4][4] = {};
    const f32x4* Ut4 = (const f32x4*)Ut;
    #pragma unroll 8
    for (int t=0;t<NCTRL;t++){
        f32x4 u = Ut4[t*256 + tid];
        #pragma unroll
        for (int kpi=0;kpi<4;kpi++){
            float s0 = sw0[kpi][t], s1 = sw1[kpi][t];
            #pragma unroll
            for (int i=0;i<4;i++){ bx[kpi][i] += u[i]*s0; by[kpi][i] += u[i]*s1; }
        }
    }

    f32x4 pga = *(const f32x4*)&pgn[2*g0];
    f32x4 pgb = *(const f32x4*)&pgn[2*g0+4];
    float px[4] = {pga[0], pga[2], pgb[0], pgb[2]};
    float py[4] = {pga[1], pga[3], pgb[1], pgb[3]};
    const float* ic0 = imgs + (size_t)b*3*HOImg*HOImg;
    const float* ic1 = ic0 + (size_t)HOImg*HOImg;
    const float* ic2 = ic1 + (size_t)HOImg*HOImg;

    #pragma unroll
    for (int kpi=0;kpi<4;kpi++){
        float a00=sa[kpi][0], a01=sa[kpi][1], a10=sa[kpi][2];
        float a11=sa[kpi][3], a20=sa[kpi][4], a21=sa[kpi][5];
        float vminx = sv[kpi][0], vminy = sv[kpi][1];
        f32x4 o0, o1, o2;
        #pragma unroll
        for (int i=0;i<4;i++){
            float zx = a00 + a10*px[i] + a20*py[i];
            float zy = a01 + a11*px[i] + a21*py[i];
            float wnx = px[i] + (zx + bx[kpi][i]);
            float wny = py[i] + (zy + by[kpi][i]);
            float wxr = (wnx - 0.35f)/0.3f*ptpx + vminx;
            float wyr = (wny - 0.35f)/0.3f*ptpy + vminy;
            float ix = ((wxr + 1.f)*512.f - 1.f)*0.5f;
            float iy = ((wyr + 1.f)*512.f - 1.f)*0.5f;
            float x0f = floorf(ix), y0f = floorf(iy);
            float fx = ix-x0f, fy = iy-y0f;
            float w00=(1.f-fx)*(1.f-fy), w10=fx*(1.f-fy), w01=(1.f-fx)*fy, w11=fx*fy;
            bool vx0 = (x0f>=0.f)&&(x0f<=511.f), vx1 = (x0f+1.f>=0.f)&&(x0f+1.f<=511.f);
            bool vy0 = (y0f>=0.f)&&(y0f<=511.f), vy1 = (y0f+1.f>=0.f)&&(y0f+1.f<=511.f);
            float m00 = (vx0&&vy0)?w00:0.f;
            float m10 = (vx1&&vy0)?w10:0.f;
            float m01 = (vx0&&vy1)?w01:0.f;
            float m11 = (vx1&&vy1)?w11:0.f;
            int X0 = (int)fminf(fmaxf(x0f,0.f),511.f);
            int X1 = (int)fminf(fmaxf(x0f+1.f,0.f),511.f);
            int Y0 = (int)fminf(fmaxf(y0f,0.f),511.f);
            int Y1 = (int)fminf(fmaxf(y0f+1.f,0.f),511.f);
            int i00 = Y0*HOImg+X0, i10 = Y0*HOImg+X1, i01 = Y1*HOImg+X0, i11 = Y1*HOImg+X1;
            o0[i] = ic0[i00]*m00 + ic0[i10]*m10 + ic0[i01]*m01 + ic0[i11]*m11;
            o1[i] = ic1[i00]*m00 + ic1[i10]*m10 + ic1[i01]*m01 + ic1[i11]*m11;
            o2[i] = ic2[i00]*m00 + ic2[i10]*m10 + ic2[i01]*m01 + ic2[i11]*m11;
        }
        const int m = m0 + kpi;
        *(f32x4*)&out[((size_t)(m*3+0))*GG + g0] = o0;
        *(f32x4*)&out[((size_t)(m*3+1))*GG + g0] = o1;
        *(f32x4*)&out[((size_t)(m*3+2))*GG + g0] = o2;
    }
}

// ============================ launcher =======================================
extern "C" void kernel_launch(void* const* d_in, const int* in_sizes, int n_in,
                              void* d_out, int out_size, void* d_ws, size_t ws_size,
                              hipStream_t stream)
{
    const float* x    = (const float*)d_in[0];
    const float* imgs = (const float*)d_in[1];
    const int*   kp   = (const int*)d_in[2];
    const float* c1w  = (const float*)d_in[3];
    const float* c2w  = (const float*)d_in[4];
    const float* l1w  = (const float*)d_in[5];
    const float* l1b  = (const float*)d_in[6];
    const float* l2w  = (const float*)d_in[7];
    const float* l2b  = (const float*)d_in[8];
    const float* l3w  = (const float*)d_in[9];
    const float* l3b  = (const float*)d_in[10];
    float* out = (float*)d_out;

    char* W = (char*)d_ws;
    short* xph   = (short*)(W + 0);                    // 12,979,200 B (bf16 single)
    float* Theta = (float*)(W + 0);                    // 32,514,048 B (aliases xp)
    constexpr size_t OFF_HH = 32514048;
    short* hh = (short*)(W + OFF_HH);                  // 17,039,360 B (bf16 single)
    float* th0   = (float*)(W + OFF_HH);               // aliases hh after conv2
    float* th1   = (float*)(W + OFF_HH + 1048576);
    float* th2   = (float*)(W + OFF_HH + 3145728);
    float* theta = (float*)(W + OFF_HH + 5242880);
    float* Ut    = (float*)(W + OFF_HH + 6324224);
    float* pgn   = (float*)(W + OFF_HH + 6586368);
    float* cbuf  = (float*)(W + OFF_HH + 6594560);
    float* ctrl  = (float*)(W + OFF_HH + 6594816);
    constexpr size_t OFF_B = OFF_HH + 17039360;        // 49,553,408
    short* B1 = (short*)(W + OFF_B);                   // 221,184 B
    short* B2 = (short*)(W + OFF_B + 221184);          // 294,912 B

    hipLaunchKernelGGL(prep_xb_k, dim3(2,130,4), dim3(256), 0, stream, x, xph);
    hipLaunchKernelGGL(prep_misc_k, dim3(768), dim3(256), 0, stream,
                       c1w, c2w, B1, B2, hh);

    hipLaunchKernelGGL((convm_k<96,130,128,128,true>), dim3(4,64,4), dim3(256), 0, stream,
                       xph, B1, hh, (float*)nullptr);
    hipLaunchKernelGGL((convm_k<128,128,126,126,false>), dim3(4,63,4), dim3(256), 0, stream,
                       hh, B2, (short*)nullptr, Theta);

    hipLaunchKernelGGL(interp_k, dim3(MM), dim3(128), 0, stream, Theta, kp, th0);
    hipLaunchKernelGGL(lin1_k, dim3(MM/8), dim3(256), 0, stream, th0, l1w, l1b, th1);
    hipLaunchKernelGGL(lin2_k, dim3(MM/8), dim3(256), 0, stream, th1, l2w, l2b, th2);
    hipLaunchKernelGGL(lin3_k, dim3(MM/8), dim3(256), 0, stream, th2, l3w, l3b, theta);
    hipLaunchKernelGGL(consts_red_k, dim3(1), dim3(1024), 0, stream, cbuf, pgn, ctrl);
    hipLaunchKernelGGL(ut_fill_k, dim3(64), dim3(256), 0, stream, pgn, ctrl, Ut);
    hipLaunchKernelGGL(warp_sample4_k, dim3(MM/4), dim3(256), 0, stream,
                       theta, kp, Ut, pgn, cbuf, imgs, out);
}